// Round 1
// 546.978 us; speedup vs baseline: 1.0125x; 1.0125x over previous
//
#include <hip/hip_runtime.h>
#include <stdint.h>

// Problem dims (fixed by reference)
#define B_ 4
#define S_ 2048
#define D_ 1024
#define H_ 16
#define DFF_ 4096
#define QSTR 3072  // fused QKV output width

typedef __attribute__((ext_vector_type(8))) short short8;
typedef __attribute__((ext_vector_type(4))) short short4v;
typedef __attribute__((ext_vector_type(4))) float floatx4;
typedef __attribute__((ext_vector_type(16))) float floatx16;

typedef const __attribute__((address_space(1))) void* gas_ptr;
typedef __attribute__((address_space(3))) void* las_ptr;

__device__ __forceinline__ short f2bf(float f) {
  union { float f; uint32_t u; } v; v.f = f;
  uint32_t r = v.u + 0x7fffu + ((v.u >> 16) & 1u);
  return (short)(r >> 16);
}

// ---------------------------------------------------------------------------
// LayerNorm: fp32 row in -> bf16 row out.  One block per row, 256 threads.
// ---------------------------------------------------------------------------
__global__ __launch_bounds__(256) void ln_kernel(
    const float* __restrict__ x, const float* __restrict__ g,
    const float* __restrict__ be, short* __restrict__ out)
{
  const int row = blockIdx.x;
  const int tid = threadIdx.x;
  const float4 v = ((const float4*)(x + (size_t)row * D_))[tid];
  float s1 = v.x + v.y + v.z + v.w;
  float s2 = v.x*v.x + v.y*v.y + v.z*v.z + v.w*v.w;
#pragma unroll
  for (int off = 1; off < 64; off <<= 1) {
    s1 += __shfl_xor(s1, off);
    s2 += __shfl_xor(s2, off);
  }
  __shared__ float r1[4], r2[4];
  if ((tid & 63) == 0) { r1[tid >> 6] = s1; r2[tid >> 6] = s2; }
  __syncthreads();
  s1 = r1[0] + r1[1] + r1[2] + r1[3];
  s2 = r2[0] + r2[1] + r2[2] + r2[3];
  const float mu = s1 * (1.0f / D_);
  const float var = s2 * (1.0f / D_) - mu * mu;
  const float rs = rsqrtf(var + 1e-5f);
  const float4 gv = ((const float4*)g)[tid];
  const float4 bv = ((const float4*)be)[tid];
  short4v o;
  o.x = f2bf((v.x - mu) * rs * gv.x + bv.x);
  o.y = f2bf((v.y - mu) * rs * gv.y + bv.y);
  o.z = f2bf((v.z - mu) * rs * gv.z + bv.z);
  o.w = f2bf((v.w - mu) * rs * gv.w + bv.w);
  *(short4v*)&out[(size_t)row * D_ + tid * 4] = o;
}

// ---------------------------------------------------------------------------
// Batched weight transpose + cast: all six weights in ONE launch.
// ---------------------------------------------------------------------------
__global__ __launch_bounds__(256) void transpose_all(
    const float* __restrict__ wq, const float* __restrict__ wk,
    const float* __restrict__ wv, const float* __restrict__ wo,
    const float* __restrict__ w1, const float* __restrict__ w2,
    short* __restrict__ wqkvT, short* __restrict__ woT,
    short* __restrict__ w1T, short* __restrict__ w2T)
{
  const uint32_t pid = blockIdx.x;
  const float* in; short* out;
  int R, C, tile, xsh;
  if (pid < 4096) {
    const int which = pid >> 10; tile = pid & 1023;
    R = 1024; C = 1024; xsh = 5;
    in  = (which == 0) ? wq : (which == 1) ? wk : (which == 2) ? wv : wo;
    out = (which == 3) ? woT : wqkvT + (size_t)which * 1024 * 1024;
  } else if (pid < 8192) {
    tile = pid - 4096; R = 1024; C = 4096; xsh = 7; in = w1; out = w1T;
  } else {
    tile = pid - 8192; R = 4096; C = 1024; xsh = 5; in = w2; out = w2T;
  }
  const int c0 = (tile & ((1 << xsh) - 1)) * 32;
  const int r0 = (tile >> xsh) * 32;

  __shared__ float t[32][33];
  const int tx = threadIdx.x & 31, ty = threadIdx.x >> 5;
#pragma unroll
  for (int i = 0; i < 4; i++)
    t[ty + i * 8][tx] = in[(size_t)(r0 + ty + i * 8) * C + c0 + tx];
  __syncthreads();
#pragma unroll
  for (int i = 0; i < 4; i++)
    out[(size_t)(c0 + ty + i * 8) * R + r0 + tx] = f2bf(t[tx][ty + i * 8]);
}

// ---------------------------------------------------------------------------
// bf16 GEMM (128x128): C[M,N] = A[M,K] @ Bt[N,K]^T.  (unchanged, R9/R11-proven)
// ---------------------------------------------------------------------------
__global__ __launch_bounds__(256, 4) void gemm_bt(
    const short* __restrict__ A, const short* __restrict__ Bt,
    float* __restrict__ outf, short* __restrict__ outb,
    short* __restrict__ outbK, short* __restrict__ vtT,
    const float* __restrict__ bias, const float* __restrict__ resid,
    int M, int N, int K, int do_relu, int split, int group)
{
  __shared__ short As[2 * 128 * 32];   // [half][row][32]
  __shared__ short Bs[2 * 128 * 32];
  const int tid = threadIdx.x;
  const int wave = tid >> 6;
  const int lane = tid & 63;
  const int quad = lane >> 4;
  const int l16 = lane & 15;

  const uint32_t nblk = gridDim.x;
  const uint32_t pid = blockIdx.y * nblk + blockIdx.x;
  const uint32_t nig = (uint32_t)group * nblk;
  const uint32_t gid = pid / nig;
  const uint32_t within = pid - gid * nig;
  const uint32_t bm = gid * group + within % group;
  const uint32_t bn = within / group;
  const int tm = bm * 128;
  const int tn = bn * 128;

  const int wm = (wave & 1) * 64;
  const int wn = (wave >> 1) * 64;
  const int srow = lane >> 2;
  const int scol = (lane & 3) * 8;

  floatx4 acc[4][4];
#pragma unroll
  for (int i = 0; i < 4; i++)
#pragma unroll
    for (int j = 0; j < 4; j++) acc[i][j] = floatx4{0.f, 0.f, 0.f, 0.f};

  const short* gA0 = A + (size_t)(tm + wave * 32 + srow) * K + scol;
  const short* gB0 = Bt + (size_t)(tn + wave * 32 + srow) * K + scol;

  for (int kt = 0; kt < K; kt += 64) {
    __syncthreads();
    __builtin_amdgcn_global_load_lds((gas_ptr)(gA0 + kt),                      (las_ptr)(&As[wave * 1024]),        16, 0, 0);
    __builtin_amdgcn_global_load_lds((gas_ptr)(gA0 + kt + (size_t)16 * K),     (las_ptr)(&As[wave * 1024 + 512]),  16, 0, 0);
    __builtin_amdgcn_global_load_lds((gas_ptr)(gB0 + kt),                      (las_ptr)(&Bs[wave * 1024]),        16, 0, 0);
    __builtin_amdgcn_global_load_lds((gas_ptr)(gB0 + kt + (size_t)16 * K),     (las_ptr)(&Bs[wave * 1024 + 512]),  16, 0, 0);
    __builtin_amdgcn_global_load_lds((gas_ptr)(gA0 + kt + 32),                 (las_ptr)(&As[4096 + wave * 1024]),       16, 0, 0);
    __builtin_amdgcn_global_load_lds((gas_ptr)(gA0 + kt + 32 + (size_t)16 * K),(las_ptr)(&As[4096 + wave * 1024 + 512]), 16, 0, 0);
    __builtin_amdgcn_global_load_lds((gas_ptr)(gB0 + kt + 32),                 (las_ptr)(&Bs[4096 + wave * 1024]),       16, 0, 0);
    __builtin_amdgcn_global_load_lds((gas_ptr)(gB0 + kt + 32 + (size_t)16 * K),(las_ptr)(&Bs[4096 + wave * 1024 + 512]), 16, 0, 0);
    __syncthreads();

#pragma unroll
    for (int ksub = 0; ksub < 2; ksub++) {
      const int hb = ksub * 4096;
      short8 af[4], bfv[4];
#pragma unroll
      for (int mi = 0; mi < 4; mi++)
        af[mi] = *(const short8*)&As[hb + (wm + mi * 16 + l16) * 32 + quad * 8];
#pragma unroll
      for (int ni = 0; ni < 4; ni++)
        bfv[ni] = *(const short8*)&Bs[hb + (wn + ni * 16 + l16) * 32 + quad * 8];
#pragma unroll
      for (int mi = 0; mi < 4; mi++)
#pragma unroll
        for (int ni = 0; ni < 4; ni++)
          acc[mi][ni] = __builtin_amdgcn_mfma_f32_16x16x32_bf16(af[mi], bfv[ni], acc[mi][ni], 0, 0, 0);
    }
  }

  short* ob = outb;
  int Nst = N;
  int cbase = tn;
  int vpart = 0;
  if (split) {
    const int part = tn >> 10;
    if (part == 2) vpart = 1;
    else ob = (part == 0) ? outb : outbK;
    Nst = D_;
    cbase = tn & (D_ - 1);
  }

  if (vpart) {
#pragma unroll
    for (int mi = 0; mi < 4; mi++) {
      const int row0 = tm + wm + mi * 16 + quad * 4;
      const int bb = row0 >> 11, s0r = row0 & 2047;
#pragma unroll
      for (int ni = 0; ni < 4; ni++) {
        const int cst = cbase + wn + ni * 16 + l16;
        short4v o;
#pragma unroll
        for (int r = 0; r < 4; r++) o[r] = f2bf(acc[mi][ni][r]);
        *(short4v*)&vtT[((size_t)(bb << 10) + cst) * (size_t)S_ + s0r] = o;
      }
    }
    return;
  }

#pragma unroll
  for (int mi = 0; mi < 4; mi++) {
    const int row0 = tm + wm + mi * 16 + quad * 4;
#pragma unroll
    for (int ni = 0; ni < 4; ni++) {
      const int col = tn + wn + ni * 16 + l16;
      const int cst = cbase + wn + ni * 16 + l16;
      const float bv = bias ? bias[col] : 0.0f;
#pragma unroll
      for (int r = 0; r < 4; r++) {
        const size_t idx = (size_t)(row0 + r) * Nst + cst;
        float v = acc[mi][ni][r] + bv;
        if (do_relu) v = fmaxf(v, 0.0f);
        if (resid) v += resid[idx];
        if (outf) outf[idx] = v;
        if (ob) ob[idx] = f2bf(v);
      }
    }
  }
}

// ---------------------------------------------------------------------------
// bf16 GEMM (128x64) for N=1024 launches (AO, FFN2).  (unchanged, R10-proven)
// ---------------------------------------------------------------------------
__global__ __launch_bounds__(256, 4) void gemm_bt_n64(
    const short* __restrict__ A, const short* __restrict__ Bt,
    float* __restrict__ outf,
    const float* __restrict__ bias, const float* __restrict__ resid,
    int M, int N, int K, int group)
{
  __shared__ short As[2 * 128 * 32];
  __shared__ short Bs[2 * 64 * 32];
  const int tid = threadIdx.x;
  const int wave = tid >> 6;
  const int lane = tid & 63;
  const int quad = lane >> 4;
  const int l16 = lane & 15;

  const uint32_t nblk = gridDim.x;
  const uint32_t pid = blockIdx.y * nblk + blockIdx.x;
  const uint32_t nig = (uint32_t)group * nblk;
  const uint32_t gid = pid / nig;
  const uint32_t within = pid - gid * nig;
  const uint32_t bm = gid * group + within % group;
  const uint32_t bn = within / group;
  const int tm = bm * 128;
  const int tn = bn * 64;

  const int wm = (wave & 1) * 64;
  const int wn = (wave >> 1) * 32;
  const int srow = lane >> 2;
  const int scol = (lane & 3) * 8;

  floatx4 acc[4][2];
#pragma unroll
  for (int i = 0; i < 4; i++)
#pragma unroll
    for (int j = 0; j < 2; j++) acc[i][j] = floatx4{0.f, 0.f, 0.f, 0.f};

  const short* gA0 = A + (size_t)(tm + wave * 32 + srow) * K + scol;
  const short* gB0 = Bt + (size_t)(tn + wave * 16 + srow) * K + scol;

  for (int kt = 0; kt < K; kt += 64) {
    __syncthreads();
    __builtin_amdgcn_global_load_lds((gas_ptr)(gA0 + kt),                      (las_ptr)(&As[wave * 1024]),        16, 0, 0);
    __builtin_amdgcn_global_load_lds((gas_ptr)(gA0 + kt + (size_t)16 * K),     (las_ptr)(&As[wave * 1024 + 512]),  16, 0, 0);
    __builtin_amdgcn_global_load_lds((gas_ptr)(gA0 + kt + 32),                 (las_ptr)(&As[4096 + wave * 1024]),       16, 0, 0);
    __builtin_amdgcn_global_load_lds((gas_ptr)(gA0 + kt + 32 + (size_t)16 * K),(las_ptr)(&As[4096 + wave * 1024 + 512]), 16, 0, 0);
    __builtin_amdgcn_global_load_lds((gas_ptr)(gB0 + kt),      (las_ptr)(&Bs[wave * 512]),        16, 0, 0);
    __builtin_amdgcn_global_load_lds((gas_ptr)(gB0 + kt + 32), (las_ptr)(&Bs[2048 + wave * 512]), 16, 0, 0);
    __syncthreads();

#pragma unroll
    for (int ksub = 0; ksub < 2; ksub++) {
      const int ha = ksub * 4096;
      const int hbv = ksub * 2048;
      short8 af[4], bfv[2];
#pragma unroll
      for (int mi = 0; mi < 4; mi++)
        af[mi] = *(const short8*)&As[ha + (wm + mi * 16 + l16) * 32 + quad * 8];
#pragma unroll
      for (int ni = 0; ni < 2; ni++)
        bfv[ni] = *(const short8*)&Bs[hbv + (wn + ni * 16 + l16) * 32 + quad * 8];
#pragma unroll
      for (int mi = 0; mi < 4; mi++)
#pragma unroll
        for (int ni = 0; ni < 2; ni++)
          acc[mi][ni] = __builtin_amdgcn_mfma_f32_16x16x32_bf16(af[mi], bfv[ni], acc[mi][ni], 0, 0, 0);
    }
  }

#pragma unroll
  for (int mi = 0; mi < 4; mi++) {
    const int row0 = tm + wm + mi * 16 + quad * 4;
#pragma unroll
    for (int ni = 0; ni < 2; ni++) {
      const int col = tn + wn + ni * 16 + l16;
      const float bv = bias ? bias[col] : 0.0f;
#pragma unroll
      for (int r = 0; r < 4; r++) {
        const size_t idx = (size_t)(row0 + r) * N + col;
        float v = acc[mi][ni][r] + bv;
        if (resid) v += resid[idx];
        outf[idx] = v;
      }
    }
  }
}

// ---------------------------------------------------------------------------
// Flash attention, R12: swapped QK^T (mfma(K,Q)) with 32x32x16 MFMA,
// in-register softmax + P relayout via v_cvt_pk_bf16_f32 + v_permlane32_swap
// (T12) -- eliminates the P LDS round-trip; double-buffered K/V staging with
// ONE barrier per 64-key tile; XOR-swizzled [64][64] K/V tiles (16B-aligned
// ds_read_b128, conflict-free column-slice reads).
//
// Layouts (32x32x16 bf16 MFMA, C: col=lane&31, row=(reg&3)+8*(reg>>2)+4*hi):
//   QK^T = mfma(Kfrag, Qfrag): lane owns ONE q (=l31), 16 k per 32-k subtile:
//     k = (reg&3) + 4*hi + 8*(reg>>2)   (reg 0..15 spans k 0..31)
//   PV A-frag needs lane=q-row l31, elems = k 8*hi + i.  Per 16-k window:
//     {a,b} = permlane32_swap(cvtpk(p0,p1), cvtpk(p4,p5)) -> words 0,2
//     {c,d} = permlane32_swap(cvtpk(p2,p3), cvtpk(p6,p7)) -> words 1,3
// ---------------------------------------------------------------------------
__device__ __forceinline__ int kvidx(int row, int scol) {
  // row-major [64][64] shorts, byte ^= (row&7)<<4  (G4 swizzle, 16B granules)
  return (row << 6) + (scol ^ ((row & 7) << 3));
}

__global__ __launch_bounds__(256, 4) void attn_kernel(
    const short* __restrict__ qb, const short* __restrict__ kb,
    const short* __restrict__ vtb, short* __restrict__ attb)
{
  __shared__ short Ks[2][64 * 64];
  __shared__ short Vts[2][64 * 64];
  __shared__ float lbuf[4][32];

  const int tid = threadIdx.x;
  const int wave = tid >> 6, lane = tid & 63;
  const int l31 = lane & 31, hi = lane >> 5;
  const int qt = blockIdx.x, bh = blockIdx.y;   // qt: 0..15 (128 q each)
  const int b = bh >> 4, h = bh & 15;
  const size_t rowbase = (size_t)b * S_;
  const int hcol = h * 64;
  const int r = tid >> 2, c = (tid & 3) * 16;   // staging: row r, shorts [c,c+16)

  // Q fragments (B-operand: row=q=l31 within wave's 32, elems d=st*16+hi*8+i),
  // prescaled by log2(e)/8.
  short8 qf[4];
  {
    const short* gq = qb + (rowbase + qt * 128 + wave * 32 + l31) * D_ + hcol + hi * 8;
#pragma unroll
    for (int st = 0; st < 4; st++) {
      short8 t = *(const short8*)(gq + st * 16);
#pragma unroll
      for (int i = 0; i < 8; i++) {
        const float f = __uint_as_float(((uint32_t)(uint16_t)t[i]) << 16) * 0.18033688f;
        t[i] = (short)((__float_as_uint(f) + 0x8000u) >> 16);
      }
      qf[st] = t;
    }
  }

  floatx16 Of[2];
#pragma unroll
  for (int nd = 0; nd < 2; nd++)
#pragma unroll
    for (int i = 0; i < 16; i++) Of[nd][i] = 0.f;
  float lrun = 0.f;

  const short* gk0 = kb + (rowbase + r) * D_ + hcol + c;          // r = k-row
  const short* gv0 = vtb + ((size_t)bh * 64 + r) * S_ + c;        // r = d-row

  // prefetch + stage tile 0 into buf 0
  short8 kr0 = *(const short8*)gk0, kr1 = *(const short8*)(gk0 + 8);
  short8 vr0 = *(const short8*)gv0, vr1 = *(const short8*)(gv0 + 8);
  *(short8*)&Ks[0][kvidx(r, c)]      = kr0;
  *(short8*)&Ks[0][kvidx(r, c + 8)]  = kr1;
  *(short8*)&Vts[0][kvidx(r, c)]     = vr0;
  *(short8*)&Vts[0][kvidx(r, c + 8)] = vr1;

  for (int kt = 0; kt < S_; kt += 64) {
    const int cur = (kt >> 6) & 1;
    const bool more = (kt + 64 < S_);
    if (more) {  // issue next-tile global loads; they land during compute
      const short* gk = gk0 + (size_t)(kt + 64) * D_;
      const short* gv = gv0 + (kt + 64);
      kr0 = *(const short8*)gk; kr1 = *(const short8*)(gk + 8);
      vr0 = *(const short8*)gv; vr1 = *(const short8*)(gv + 8);
    }
    __syncthreads();  // buf[cur] staged by all waves

#pragma unroll
    for (int sub = 0; sub < 2; sub++) {
      // S^T[k, q] over 32 k-rows, K-dim = d (4 chained MFMAs)
      floatx16 s;
#pragma unroll
      for (int i = 0; i < 16; i++) s[i] = 0.f;
#pragma unroll
      for (int st = 0; st < 4; st++) {
        const short8 kf = *(const short8*)&Ks[cur][kvidx(sub * 32 + l31, st * 16 + hi * 8)];
        s = __builtin_amdgcn_mfma_f32_32x32x16_bf16(kf, qf[st], s, 0, 0, 0);
      }
      // softmax numerator, in-register (lane-local: one q per lane)
      float p[16];
#pragma unroll
      for (int i = 0; i < 16; i++) { p[i] = __builtin_amdgcn_exp2f(s[i]); lrun += p[i]; }
      // pack P into PV A-frags: per 16-k window 4 cvt_pk + 2 permlane32_swap
      short8 pf[2];
#pragma unroll
      for (int kw = 0; kw < 2; kw++) {
        const int o = kw * 8;
        uint32_t wa, wb, wc, wd;
        asm("v_cvt_pk_bf16_f32 %0, %1, %2" : "=v"(wa) : "v"(p[o + 0]), "v"(p[o + 1]));
        asm("v_cvt_pk_bf16_f32 %0, %1, %2" : "=v"(wb) : "v"(p[o + 4]), "v"(p[o + 5]));
        asm("v_cvt_pk_bf16_f32 %0, %1, %2" : "=v"(wc) : "v"(p[o + 2]), "v"(p[o + 3]));
        asm("v_cvt_pk_bf16_f32 %0, %1, %2" : "=v"(wd) : "v"(p[o + 6]), "v"(p[o + 7]));
        asm("v_permlane32_swap_b32 %0, %1" : "+v"(wa), "+v"(wb));
        asm("v_permlane32_swap_b32 %0, %1" : "+v"(wc), "+v"(wd));
        union { uint32_t u[4]; short8 s8; } pk;
        pk.u[0] = wa; pk.u[1] = wc; pk.u[2] = wb; pk.u[3] = wd;
        pf[kw] = pk.s8;
      }
      // PV: O[q, d] += P[q, k-window] * Vt[d, k-window]
#pragma unroll
      for (int kw = 0; kw < 2; kw++)
#pragma unroll
        for (int nd = 0; nd < 2; nd++) {
          const short8 vf = *(const short8*)&Vts[cur][kvidx(nd * 32 + l31, sub * 32 + kw * 16 + hi * 8)];
          Of[nd] = __builtin_amdgcn_mfma_f32_32x32x16_bf16(pf[kw], vf, Of[nd], 0, 0, 0);
        }
    }

    if (more) {  // write next tile into the other buffer (no barrier needed)
      const int nxt = cur ^ 1;
      *(short8*)&Ks[nxt][kvidx(r, c)]      = kr0;
      *(short8*)&Ks[nxt][kvidx(r, c + 8)]  = kr1;
      *(short8*)&Vts[nxt][kvidx(r, c)]     = vr0;
      *(short8*)&Vts[nxt][kvidx(r, c + 8)] = vr1;
    }
  }

  // l: lane's partial covers half the k per q; partner lane (hi^1) has the rest
  const float ltot = lrun + __shfl_xor(lrun, 32);
  if (hi == 0) lbuf[wave][l31] = ltot;
  asm volatile("" ::: "memory");  // wave-private LDS; compiler orders via lgkmcnt
#pragma unroll
  for (int reg = 0; reg < 16; reg++) {
    const int q = (reg & 3) + 4 * hi + 8 * (reg >> 2);
    const float inv = 1.0f / lbuf[wave][q];
    const size_t base = (rowbase + qt * 128 + wave * 32 + q) * D_ + hcol + l31;
    attb[base]      = f2bf(Of[0][reg] * inv);
    attb[base + 32] = f2bf(Of[1][reg] * inv);
  }
}

// ---------------------------------------------------------------------------
extern "C" void kernel_launch(void* const* d_in, const int* in_sizes, int n_in,
                              void* d_out, int out_size, void* d_ws, size_t ws_size,
                              hipStream_t stream) {
  const float* x   = (const float*)d_in[0];
  const float* wq  = (const float*)d_in[1];
  const float* wk  = (const float*)d_in[2];
  const float* wv  = (const float*)d_in[3];
  const float* wo  = (const float*)d_in[4];
  const float* w1  = (const float*)d_in[5];
  const float* b1  = (const float*)d_in[6];
  const float* w2  = (const float*)d_in[7];
  const float* b2  = (const float*)d_in[8];
  const float* g1  = (const float*)d_in[9];
  const float* be1 = (const float*)d_in[10];
  const float* g2  = (const float*)d_in[11];
  const float* be2 = (const float*)d_in[12];
  float* out = (float*)d_out;

  const size_t MROWS = (size_t)B_ * S_;  // 8192
  char* p = (char*)d_ws;
  auto take = [&](size_t bytes) { char* r = p; p += (bytes + 255) & ~(size_t)255; return r; };
  short* hb    = (short*)take(MROWS * D_ * 2);   // LN1 out
  short* h2b   = (short*)take(MROWS * D_ * 2);
  short* qbuf  = (short*)take(MROWS * D_ * 2);
  short* kbuf  = (short*)take(MROWS * D_ * 2);
  short* vtb   = (short*)take(MROWS * D_ * 2);   // V transposed (written by QKV GEMM)
  short* attb  = (short*)take(MROWS * D_ * 2);
  short* ffb   = (short*)take(MROWS * DFF_ * 2);
  short* wqkvT = (short*)take((size_t)3 * D_ * D_ * 2);
  short* woT   = (short*)take((size_t)D_ * D_ * 2);
  short* w1T   = (short*)take((size_t)D_ * DFF_ * 2);
  short* w2T   = (short*)take((size_t)DFF_ * D_ * 2);
  float* x1    = (float*)take(MROWS * D_ * 4);

  transpose_all<<<12288, 256, 0, stream>>>(wq, wk, wv, wo, w1, w2,
                                           wqkvT, woT, w1T, w2T);

  ln_kernel<<<MROWS, 256, 0, stream>>>(x, g1, be1, hb);

  gemm_bt<<<dim3(QSTR / 128, MROWS / 128), 256, 0, stream>>>(
      hb, wqkvT, nullptr, qbuf, kbuf, vtb, nullptr, nullptr, MROWS, QSTR, D_, 0, 1, 8);

  attn_kernel<<<dim3(S_ / 128, B_ * H_), 256, 0, stream>>>(qbuf, kbuf, vtb, attb);

  gemm_bt_n64<<<dim3(D_ / 64, MROWS / 128), 256, 0, stream>>>(
      attb, woT, x1, nullptr, x, MROWS, D_, D_, 8);

  ln_kernel<<<MROWS, 256, 0, stream>>>(x1, g2, be2, h2b);

  gemm_bt<<<dim3(DFF_ / 128, MROWS / 128), 256, 0, stream>>>(
      h2b, w1T, nullptr, ffb, nullptr, nullptr, b1, nullptr, MROWS, DFF_, D_, 1, 0, 8);

  gemm_bt_n64<<<dim3(D_ / 64, MROWS / 128), 256, 0, stream>>>(
      ffb, w2T, out, b2, x1, MROWS, D_, DFF_, 4);

  (void)in_sizes; (void)n_in; (void)out_size; (void)ws_size;
}

// Round 3
// 525.406 us; speedup vs baseline: 1.0541x; 1.0411x over previous
//
#include <hip/hip_runtime.h>
#include <stdint.h>

// Problem dims (fixed by reference)
#define B_ 4
#define S_ 2048
#define D_ 1024
#define H_ 16
#define DFF_ 4096
#define QSTR 3072  // fused QKV output width

typedef __attribute__((ext_vector_type(8))) short short8;
typedef __attribute__((ext_vector_type(4))) short short4v;
typedef __attribute__((ext_vector_type(4))) float floatx4;
typedef __attribute__((ext_vector_type(16))) float floatx16;

typedef const __attribute__((address_space(1))) void* gas_ptr;
typedef __attribute__((address_space(3))) void* las_ptr;

__device__ __forceinline__ short f2bf(float f) {
  union { float f; uint32_t u; } v; v.f = f;
  uint32_t r = v.u + 0x7fffu + ((v.u >> 16) & 1u);
  return (short)(r >> 16);
}

// ---------------------------------------------------------------------------
// LayerNorm: fp32 row in -> bf16 row out.  One block per row, 256 threads.
// ---------------------------------------------------------------------------
__global__ __launch_bounds__(256) void ln_kernel(
    const float* __restrict__ x, const float* __restrict__ g,
    const float* __restrict__ be, short* __restrict__ out)
{
  const int row = blockIdx.x;
  const int tid = threadIdx.x;
  const float4 v = ((const float4*)(x + (size_t)row * D_))[tid];
  float s1 = v.x + v.y + v.z + v.w;
  float s2 = v.x*v.x + v.y*v.y + v.z*v.z + v.w*v.w;
#pragma unroll
  for (int off = 1; off < 64; off <<= 1) {
    s1 += __shfl_xor(s1, off);
    s2 += __shfl_xor(s2, off);
  }
  __shared__ float r1[4], r2[4];
  if ((tid & 63) == 0) { r1[tid >> 6] = s1; r2[tid >> 6] = s2; }
  __syncthreads();
  s1 = r1[0] + r1[1] + r1[2] + r1[3];
  s2 = r2[0] + r2[1] + r2[2] + r2[3];
  const float mu = s1 * (1.0f / D_);
  const float var = s2 * (1.0f / D_) - mu * mu;
  const float rs = rsqrtf(var + 1e-5f);
  const float4 gv = ((const float4*)g)[tid];
  const float4 bv = ((const float4*)be)[tid];
  short4v o;
  o.x = f2bf((v.x - mu) * rs * gv.x + bv.x);
  o.y = f2bf((v.y - mu) * rs * gv.y + bv.y);
  o.z = f2bf((v.z - mu) * rs * gv.z + bv.z);
  o.w = f2bf((v.w - mu) * rs * gv.w + bv.w);
  *(short4v*)&out[(size_t)row * D_ + tid * 4] = o;
}

// ---------------------------------------------------------------------------
// Batched weight transpose + cast: all six weights in ONE launch.
// ---------------------------------------------------------------------------
__global__ __launch_bounds__(256) void transpose_all(
    const float* __restrict__ wq, const float* __restrict__ wk,
    const float* __restrict__ wv, const float* __restrict__ wo,
    const float* __restrict__ w1, const float* __restrict__ w2,
    short* __restrict__ wqkvT, short* __restrict__ woT,
    short* __restrict__ w1T, short* __restrict__ w2T)
{
  const uint32_t pid = blockIdx.x;
  const float* in; short* out;
  int R, C, tile, xsh;
  if (pid < 4096) {
    const int which = pid >> 10; tile = pid & 1023;
    R = 1024; C = 1024; xsh = 5;
    in  = (which == 0) ? wq : (which == 1) ? wk : (which == 2) ? wv : wo;
    out = (which == 3) ? woT : wqkvT + (size_t)which * 1024 * 1024;
  } else if (pid < 8192) {
    tile = pid - 4096; R = 1024; C = 4096; xsh = 7; in = w1; out = w1T;
  } else {
    tile = pid - 8192; R = 4096; C = 1024; xsh = 5; in = w2; out = w2T;
  }
  const int c0 = (tile & ((1 << xsh) - 1)) * 32;
  const int r0 = (tile >> xsh) * 32;

  __shared__ float t[32][33];
  const int tx = threadIdx.x & 31, ty = threadIdx.x >> 5;
#pragma unroll
  for (int i = 0; i < 4; i++)
    t[ty + i * 8][tx] = in[(size_t)(r0 + ty + i * 8) * C + c0 + tx];
  __syncthreads();
#pragma unroll
  for (int i = 0; i < 4; i++)
    out[(size_t)(c0 + ty + i * 8) * R + r0 + tx] = f2bf(t[tx][ty + i * 8]);
}

// ---------------------------------------------------------------------------
// bf16 GEMM (128x128): C[M,N] = A[M,K] @ Bt[N,K]^T.  (unchanged, R9/R11-proven)
// ---------------------------------------------------------------------------
__global__ __launch_bounds__(256, 4) void gemm_bt(
    const short* __restrict__ A, const short* __restrict__ Bt,
    float* __restrict__ outf, short* __restrict__ outb,
    short* __restrict__ outbK, short* __restrict__ vtT,
    const float* __restrict__ bias, const float* __restrict__ resid,
    int M, int N, int K, int do_relu, int split, int group)
{
  __shared__ short As[2 * 128 * 32];   // [half][row][32]
  __shared__ short Bs[2 * 128 * 32];
  const int tid = threadIdx.x;
  const int wave = tid >> 6;
  const int lane = tid & 63;
  const int quad = lane >> 4;
  const int l16 = lane & 15;

  const uint32_t nblk = gridDim.x;
  const uint32_t pid = blockIdx.y * nblk + blockIdx.x;
  const uint32_t nig = (uint32_t)group * nblk;
  const uint32_t gid = pid / nig;
  const uint32_t within = pid - gid * nig;
  const uint32_t bm = gid * group + within % group;
  const uint32_t bn = within / group;
  const int tm = bm * 128;
  const int tn = bn * 128;

  const int wm = (wave & 1) * 64;
  const int wn = (wave >> 1) * 64;
  const int srow = lane >> 2;
  const int scol = (lane & 3) * 8;

  floatx4 acc[4][4];
#pragma unroll
  for (int i = 0; i < 4; i++)
#pragma unroll
    for (int j = 0; j < 4; j++) acc[i][j] = floatx4{0.f, 0.f, 0.f, 0.f};

  const short* gA0 = A + (size_t)(tm + wave * 32 + srow) * K + scol;
  const short* gB0 = Bt + (size_t)(tn + wave * 32 + srow) * K + scol;

  for (int kt = 0; kt < K; kt += 64) {
    __syncthreads();
    __builtin_amdgcn_global_load_lds((gas_ptr)(gA0 + kt),                      (las_ptr)(&As[wave * 1024]),        16, 0, 0);
    __builtin_amdgcn_global_load_lds((gas_ptr)(gA0 + kt + (size_t)16 * K),     (las_ptr)(&As[wave * 1024 + 512]),  16, 0, 0);
    __builtin_amdgcn_global_load_lds((gas_ptr)(gB0 + kt),                      (las_ptr)(&Bs[wave * 1024]),        16, 0, 0);
    __builtin_amdgcn_global_load_lds((gas_ptr)(gB0 + kt + (size_t)16 * K),     (las_ptr)(&Bs[wave * 1024 + 512]),  16, 0, 0);
    __builtin_amdgcn_global_load_lds((gas_ptr)(gA0 + kt + 32),                 (las_ptr)(&As[4096 + wave * 1024]),       16, 0, 0);
    __builtin_amdgcn_global_load_lds((gas_ptr)(gA0 + kt + 32 + (size_t)16 * K),(las_ptr)(&As[4096 + wave * 1024 + 512]), 16, 0, 0);
    __builtin_amdgcn_global_load_lds((gas_ptr)(gB0 + kt + 32),                 (las_ptr)(&Bs[4096 + wave * 1024]),       16, 0, 0);
    __builtin_amdgcn_global_load_lds((gas_ptr)(gB0 + kt + 32 + (size_t)16 * K),(las_ptr)(&Bs[4096 + wave * 1024 + 512]), 16, 0, 0);
    __syncthreads();

#pragma unroll
    for (int ksub = 0; ksub < 2; ksub++) {
      const int hb = ksub * 4096;
      short8 af[4], bfv[4];
#pragma unroll
      for (int mi = 0; mi < 4; mi++)
        af[mi] = *(const short8*)&As[hb + (wm + mi * 16 + l16) * 32 + quad * 8];
#pragma unroll
      for (int ni = 0; ni < 4; ni++)
        bfv[ni] = *(const short8*)&Bs[hb + (wn + ni * 16 + l16) * 32 + quad * 8];
#pragma unroll
      for (int mi = 0; mi < 4; mi++)
#pragma unroll
        for (int ni = 0; ni < 4; ni++)
          acc[mi][ni] = __builtin_amdgcn_mfma_f32_16x16x32_bf16(af[mi], bfv[ni], acc[mi][ni], 0, 0, 0);
    }
  }

  short* ob = outb;
  int Nst = N;
  int cbase = tn;
  int vpart = 0;
  if (split) {
    const int part = tn >> 10;
    if (part == 2) vpart = 1;
    else ob = (part == 0) ? outb : outbK;
    Nst = D_;
    cbase = tn & (D_ - 1);
  }

  if (vpart) {
#pragma unroll
    for (int mi = 0; mi < 4; mi++) {
      const int row0 = tm + wm + mi * 16 + quad * 4;
      const int bb = row0 >> 11, s0r = row0 & 2047;
#pragma unroll
      for (int ni = 0; ni < 4; ni++) {
        const int cst = cbase + wn + ni * 16 + l16;
        short4v o;
#pragma unroll
        for (int r = 0; r < 4; r++) o[r] = f2bf(acc[mi][ni][r]);
        *(short4v*)&vtT[((size_t)(bb << 10) + cst) * (size_t)S_ + s0r] = o;
      }
    }
    return;
  }

#pragma unroll
  for (int mi = 0; mi < 4; mi++) {
    const int row0 = tm + wm + mi * 16 + quad * 4;
#pragma unroll
    for (int ni = 0; ni < 4; ni++) {
      const int col = tn + wn + ni * 16 + l16;
      const int cst = cbase + wn + ni * 16 + l16;
      const float bv = bias ? bias[col] : 0.0f;
#pragma unroll
      for (int r = 0; r < 4; r++) {
        const size_t idx = (size_t)(row0 + r) * Nst + cst;
        float v = acc[mi][ni][r] + bv;
        if (do_relu) v = fmaxf(v, 0.0f);
        if (resid) v += resid[idx];
        if (outf) outf[idx] = v;
        if (ob) ob[idx] = f2bf(v);
      }
    }
  }
}

// ---------------------------------------------------------------------------
// bf16 GEMM (128x64) for N=1024 launches (AO, FFN2).  (unchanged, R10-proven)
// ---------------------------------------------------------------------------
__global__ __launch_bounds__(256, 4) void gemm_bt_n64(
    const short* __restrict__ A, const short* __restrict__ Bt,
    float* __restrict__ outf,
    const float* __restrict__ bias, const float* __restrict__ resid,
    int M, int N, int K, int group)
{
  __shared__ short As[2 * 128 * 32];
  __shared__ short Bs[2 * 64 * 32];
  const int tid = threadIdx.x;
  const int wave = tid >> 6;
  const int lane = tid & 63;
  const int quad = lane >> 4;
  const int l16 = lane & 15;

  const uint32_t nblk = gridDim.x;
  const uint32_t pid = blockIdx.y * nblk + blockIdx.x;
  const uint32_t nig = (uint32_t)group * nblk;
  const uint32_t gid = pid / nig;
  const uint32_t within = pid - gid * nig;
  const uint32_t bm = gid * group + within % group;
  const uint32_t bn = within / group;
  const int tm = bm * 128;
  const int tn = bn * 64;

  const int wm = (wave & 1) * 64;
  const int wn = (wave >> 1) * 32;
  const int srow = lane >> 2;
  const int scol = (lane & 3) * 8;

  floatx4 acc[4][2];
#pragma unroll
  for (int i = 0; i < 4; i++)
#pragma unroll
    for (int j = 0; j < 2; j++) acc[i][j] = floatx4{0.f, 0.f, 0.f, 0.f};

  const short* gA0 = A + (size_t)(tm + wave * 32 + srow) * K + scol;
  const short* gB0 = Bt + (size_t)(tn + wave * 16 + srow) * K + scol;

  for (int kt = 0; kt < K; kt += 64) {
    __syncthreads();
    __builtin_amdgcn_global_load_lds((gas_ptr)(gA0 + kt),                      (las_ptr)(&As[wave * 1024]),        16, 0, 0);
    __builtin_amdgcn_global_load_lds((gas_ptr)(gA0 + kt + (size_t)16 * K),     (las_ptr)(&As[wave * 1024 + 512]),  16, 0, 0);
    __builtin_amdgcn_global_load_lds((gas_ptr)(gA0 + kt + 32),                 (las_ptr)(&As[4096 + wave * 1024]),       16, 0, 0);
    __builtin_amdgcn_global_load_lds((gas_ptr)(gA0 + kt + 32 + (size_t)16 * K),(las_ptr)(&As[4096 + wave * 1024 + 512]), 16, 0, 0);
    __builtin_amdgcn_global_load_lds((gas_ptr)(gB0 + kt),      (las_ptr)(&Bs[wave * 512]),        16, 0, 0);
    __builtin_amdgcn_global_load_lds((gas_ptr)(gB0 + kt + 32), (las_ptr)(&Bs[2048 + wave * 512]), 16, 0, 0);
    __syncthreads();

#pragma unroll
    for (int ksub = 0; ksub < 2; ksub++) {
      const int ha = ksub * 4096;
      const int hbv = ksub * 2048;
      short8 af[4], bfv[2];
#pragma unroll
      for (int mi = 0; mi < 4; mi++)
        af[mi] = *(const short8*)&As[ha + (wm + mi * 16 + l16) * 32 + quad * 8];
#pragma unroll
      for (int ni = 0; ni < 2; ni++)
        bfv[ni] = *(const short8*)&Bs[hbv + (wn + ni * 16 + l16) * 32 + quad * 8];
#pragma unroll
      for (int mi = 0; mi < 4; mi++)
#pragma unroll
        for (int ni = 0; ni < 2; ni++)
          acc[mi][ni] = __builtin_amdgcn_mfma_f32_16x16x32_bf16(af[mi], bfv[ni], acc[mi][ni], 0, 0, 0);
    }
  }

#pragma unroll
  for (int mi = 0; mi < 4; mi++) {
    const int row0 = tm + wm + mi * 16 + quad * 4;
#pragma unroll
    for (int ni = 0; ni < 2; ni++) {
      const int col = tn + wn + ni * 16 + l16;
      const float bv = bias ? bias[col] : 0.0f;
#pragma unroll
      for (int r = 0; r < 4; r++) {
        const size_t idx = (size_t)(row0 + r) * N + col;
        float v = acc[mi][ni][r] + bv;
        if (resid) v += resid[idx];
        outf[idx] = v;
      }
    }
  }
}

// ---------------------------------------------------------------------------
// Flash attention, R13 (resubmit; R2 bench was an infra timeout):
// in-register softmax (swapped QK^T, 32x32x16 MFMA, cvt_pk +
// permlane32_swap); staging:
//  - K/V tiles staged via global_load_lds (async DMA, no staging VGPRs),
//    issued immediately AFTER the top barrier so the compiler's pre-barrier
//    vmcnt(0) drain lands after a full compute phase of overlap (m97 pattern).
//  - LDS layout: [64][64] shorts, granule (16B) swizzle g ^= swz(row),
//    swz(r) = (r&7) ^ ((r>>3)&3)  -- any 8 consecutive rows AND rows
//    {r, r+8, r+16, r+24} hit distinct granule positions (bank-spread);
//    applied by pre-permuting the GLOBAL source address (linear LDS dest,
//    rule: source perm == read perm, XOR involution).
//  - s_setprio(1) around MFMA clusters (T5).
// ---------------------------------------------------------------------------
__device__ __forceinline__ int swz64(int row) {
  return (row & 7) ^ ((row >> 3) & 3);
}
__device__ __forceinline__ int kvidx(int row, int scol) {
  // scol in shorts (multiple of 8); granule XOR-swizzled by swz64(row)
  return (row << 6) + (scol ^ (swz64(row) << 3));
}

__global__ __launch_bounds__(256, 4) void attn_kernel(
    const short* __restrict__ qb, const short* __restrict__ kb,
    const short* __restrict__ vtb, short* __restrict__ attb)
{
  __shared__ short Ks[2][64 * 64];
  __shared__ short Vts[2][64 * 64];
  __shared__ float lbuf[4][32];

  const int tid = threadIdx.x;
  const int wave = tid >> 6, lane = tid & 63;
  const int l31 = lane & 31, hi = lane >> 5;
  const int qt = blockIdx.x, bh = blockIdx.y;   // qt: 0..15 (128 q each)
  const int b = bh >> 4, h = bh & 15;
  const size_t rowbase = (size_t)b * S_;
  const int hcol = h * 64;

  // ---- staging geometry (global_load_lds: wave-uniform LDS base + lane*16B)
  // lane l covers LDS row (j*32 + wave*8 + (l>>3)), granule (l&7).
  // Source granule = (l&7) ^ swz(row); swz(row) = (l>>3) ^ wave  (j drops out).
  const int lr = lane >> 3, lg = lane & 7;
  const int sgran = (lg ^ lr ^ wave) * 8;  // source column offset in shorts
  const short* ksrc = kb + (rowbase + wave * 8 + lr) * D_ + hcol + sgran;
  const short* vsrc = vtb + ((size_t)bh * 64 + wave * 8 + lr) * S_ + sgran;

  // Q fragments (B-operand: row=q=l31 within wave's 32, elems d=st*16+hi*8+i),
  // prescaled by log2(e)/8.
  short8 qf[4];
  {
    const short* gq = qb + (rowbase + qt * 128 + wave * 32 + l31) * D_ + hcol + hi * 8;
#pragma unroll
    for (int st = 0; st < 4; st++) {
      short8 t = *(const short8*)(gq + st * 16);
#pragma unroll
      for (int i = 0; i < 8; i++) {
        const float f = __uint_as_float(((uint32_t)(uint16_t)t[i]) << 16) * 0.18033688f;
        t[i] = (short)((__float_as_uint(f) + 0x8000u) >> 16);
      }
      qf[st] = t;
    }
  }

  floatx16 Of[2];
#pragma unroll
  for (int nd = 0; nd < 2; nd++)
#pragma unroll
    for (int i = 0; i < 16; i++) Of[nd][i] = 0.f;
  float lrun0 = 0.f, lrun1 = 0.f;

  // prologue: stage tile 0 into buf 0 (4 DMA issues per wave)
  __builtin_amdgcn_global_load_lds((gas_ptr)ksrc,                      (las_ptr)(&Ks[0][(wave * 8) * 64]),        16, 0, 0);
  __builtin_amdgcn_global_load_lds((gas_ptr)(ksrc + (size_t)32 * D_),  (las_ptr)(&Ks[0][(32 + wave * 8) * 64]),   16, 0, 0);
  __builtin_amdgcn_global_load_lds((gas_ptr)vsrc,                      (las_ptr)(&Vts[0][(wave * 8) * 64]),       16, 0, 0);
  __builtin_amdgcn_global_load_lds((gas_ptr)(vsrc + (size_t)32 * S_),  (las_ptr)(&Vts[0][(32 + wave * 8) * 64]),  16, 0, 0);

  for (int kt = 0; kt < S_; kt += 64) {
    const int cur = (kt >> 6) & 1;
    __syncthreads();  // drains buf[cur] DMA (issued last iter, overlapped)

    if (kt + 64 < S_) {  // issue next-tile DMA; lands during compute below
      const int nxt = cur ^ 1;
      const short* kp = ksrc + (size_t)(kt + 64) * D_;
      const short* vp = vsrc + (kt + 64);
      __builtin_amdgcn_global_load_lds((gas_ptr)kp,                      (las_ptr)(&Ks[nxt][(wave * 8) * 64]),        16, 0, 0);
      __builtin_amdgcn_global_load_lds((gas_ptr)(kp + (size_t)32 * D_),  (las_ptr)(&Ks[nxt][(32 + wave * 8) * 64]),   16, 0, 0);
      __builtin_amdgcn_global_load_lds((gas_ptr)vp,                      (las_ptr)(&Vts[nxt][(wave * 8) * 64]),       16, 0, 0);
      __builtin_amdgcn_global_load_lds((gas_ptr)(vp + (size_t)32 * S_),  (las_ptr)(&Vts[nxt][(32 + wave * 8) * 64]),  16, 0, 0);
    }

#pragma unroll
    for (int sub = 0; sub < 2; sub++) {
      // S^T[k, q] over 32 k-rows, K-dim = d (4 chained MFMAs)
      floatx16 s;
#pragma unroll
      for (int i = 0; i < 16; i++) s[i] = 0.f;
      __builtin_amdgcn_s_setprio(1);
#pragma unroll
      for (int st = 0; st < 4; st++) {
        const short8 kf = *(const short8*)&Ks[cur][kvidx(sub * 32 + l31, st * 16 + hi * 8)];
        s = __builtin_amdgcn_mfma_f32_32x32x16_bf16(kf, qf[st], s, 0, 0, 0);
      }
      __builtin_amdgcn_s_setprio(0);
      // softmax numerator, in-register (lane-local: one q per lane)
      float p[16];
#pragma unroll
      for (int i = 0; i < 16; i++) {
        p[i] = __builtin_amdgcn_exp2f(s[i]);
        if (i & 1) lrun1 += p[i]; else lrun0 += p[i];
      }
      // pack P into PV A-frags: per 16-k window 4 cvt_pk + 2 permlane32_swap
      short8 pf[2];
#pragma unroll
      for (int kw = 0; kw < 2; kw++) {
        const int o = kw * 8;
        uint32_t wa, wb, wc, wd;
        asm("v_cvt_pk_bf16_f32 %0, %1, %2" : "=v"(wa) : "v"(p[o + 0]), "v"(p[o + 1]));
        asm("v_cvt_pk_bf16_f32 %0, %1, %2" : "=v"(wb) : "v"(p[o + 4]), "v"(p[o + 5]));
        asm("v_cvt_pk_bf16_f32 %0, %1, %2" : "=v"(wc) : "v"(p[o + 2]), "v"(p[o + 3]));
        asm("v_cvt_pk_bf16_f32 %0, %1, %2" : "=v"(wd) : "v"(p[o + 6]), "v"(p[o + 7]));
        asm("v_permlane32_swap_b32 %0, %1" : "+v"(wa), "+v"(wb));
        asm("v_permlane32_swap_b32 %0, %1" : "+v"(wc), "+v"(wd));
        union { uint32_t u[4]; short8 s8; } pk;
        pk.u[0] = wa; pk.u[1] = wc; pk.u[2] = wb; pk.u[3] = wd;
        pf[kw] = pk.s8;
      }
      // PV: O[q, d] += P[q, k-window] * Vt[d, k-window]
      __builtin_amdgcn_s_setprio(1);
#pragma unroll
      for (int kw = 0; kw < 2; kw++)
#pragma unroll
        for (int nd = 0; nd < 2; nd++) {
          const short8 vf = *(const short8*)&Vts[cur][kvidx(nd * 32 + l31, sub * 32 + kw * 16 + hi * 8)];
          Of[nd] = __builtin_amdgcn_mfma_f32_32x32x16_bf16(pf[kw], vf, Of[nd], 0, 0, 0);
        }
      __builtin_amdgcn_s_setprio(0);
    }
  }

  // l: lane's partial covers half the k per q; partner lane (hi^1) has the rest
  const float lrun = lrun0 + lrun1;
  const float ltot = lrun + __shfl_xor(lrun, 32);
  if (hi == 0) lbuf[wave][l31] = ltot;
  asm volatile("" ::: "memory");  // wave-private LDS; compiler orders via lgkmcnt
#pragma unroll
  for (int reg = 0; reg < 16; reg++) {
    const int q = (reg & 3) + 4 * hi + 8 * (reg >> 2);
    const float inv = 1.0f / lbuf[wave][q];
    const size_t base = (rowbase + qt * 128 + wave * 32 + q) * D_ + hcol + l31;
    attb[base]      = f2bf(Of[0][reg] * inv);
    attb[base + 32] = f2bf(Of[1][reg] * inv);
  }
}

// ---------------------------------------------------------------------------
extern "C" void kernel_launch(void* const* d_in, const int* in_sizes, int n_in,
                              void* d_out, int out_size, void* d_ws, size_t ws_size,
                              hipStream_t stream) {
  const float* x   = (const float*)d_in[0];
  const float* wq  = (const float*)d_in[1];
  const float* wk  = (const float*)d_in[2];
  const float* wv  = (const float*)d_in[3];
  const float* wo  = (const float*)d_in[4];
  const float* w1  = (const float*)d_in[5];
  const float* b1  = (const float*)d_in[6];
  const float* w2  = (const float*)d_in[7];
  const float* b2  = (const float*)d_in[8];
  const float* g1  = (const float*)d_in[9];
  const float* be1 = (const float*)d_in[10];
  const float* g2  = (const float*)d_in[11];
  const float* be2 = (const float*)d_in[12];
  float* out = (float*)d_out;

  const size_t MROWS = (size_t)B_ * S_;  // 8192
  char* p = (char*)d_ws;
  auto take = [&](size_t bytes) { char* r = p; p += (bytes + 255) & ~(size_t)255; return r; };
  short* hb    = (short*)take(MROWS * D_ * 2);   // LN1 out
  short* h2b   = (short*)take(MROWS * D_ * 2);
  short* qbuf  = (short*)take(MROWS * D_ * 2);
  short* kbuf  = (short*)take(MROWS * D_ * 2);
  short* vtb   = (short*)take(MROWS * D_ * 2);   // V transposed (written by QKV GEMM)
  short* attb  = (short*)take(MROWS * D_ * 2);
  short* ffb   = (short*)take(MROWS * DFF_ * 2);
  short* wqkvT = (short*)take((size_t)3 * D_ * D_ * 2);
  short* woT   = (short*)take((size_t)D_ * D_ * 2);
  short* w1T   = (short*)take((size_t)D_ * DFF_ * 2);
  short* w2T   = (short*)take((size_t)DFF_ * D_ * 2);
  float* x1    = (float*)take(MROWS * D_ * 4);

  transpose_all<<<12288, 256, 0, stream>>>(wq, wk, wv, wo, w1, w2,
                                           wqkvT, woT, w1T, w2T);

  ln_kernel<<<MROWS, 256, 0, stream>>>(x, g1, be1, hb);

  gemm_bt<<<dim3(QSTR / 128, MROWS / 128), 256, 0, stream>>>(
      hb, wqkvT, nullptr, qbuf, kbuf, vtb, nullptr, nullptr, MROWS, QSTR, D_, 0, 1, 8);

  attn_kernel<<<dim3(S_ / 128, B_ * H_), 256, 0, stream>>>(qbuf, kbuf, vtb, attb);

  gemm_bt_n64<<<dim3(D_ / 64, MROWS / 128), 256, 0, stream>>>(
      attb, woT, x1, nullptr, x, MROWS, D_, D_, 8);

  ln_kernel<<<MROWS, 256, 0, stream>>>(x1, g2, be2, h2b);

  gemm_bt<<<dim3(DFF_ / 128, MROWS / 128), 256, 0, stream>>>(
      h2b, w1T, nullptr, ffb, nullptr, nullptr, b1, nullptr, MROWS, DFF_, D_, 1, 0, 8);

  gemm_bt_n64<<<dim3(D_ / 64, MROWS / 128), 256, 0, stream>>>(
      ffb, w2T, out, b2, x1, MROWS, D_, DFF_, 4);

  (void)in_sizes; (void)n_in; (void)out_size; (void)ws_size;
}